// Round 17
// baseline (114.424 us; speedup 1.0000x reference)
//
#include <hip/hip_runtime.h>
#include <hip/hip_fp16.h>
#include <math.h>

// Softmax splatting: B=8, C=4, H=512, W=960, fp32.
// R17: R16 structure (2x2 quad gather, RAD=3, per-tile buckets) +
//  (1) alternating row stride 41/42 -> two-row stride 166 dwords == 6 mod 32
//      -> qy-group phases {0,6,12,18}: kills the 4-way b64 bank conflict;
//  (2) f32x2 packed accumulate (v_pk_fma_f32 via __builtin_elementwise_fma).
// Numerics frozen (proven): flow f32, im f32, abs coords, channels f16,
// runtime dyi loop.

typedef float f32x2 __attribute__((ext_vector_type(2)));

#define EPS 1e-7f

constexpr int B = 8, C = 4, H = 512, W = 960;
constexpr int HW = H * W;            // 491520
constexpr int CHW = C * HW;          // 1966080
constexpr int NPIX = B * HW;         // 3932160

constexpr int TX = 32, TY = 32;      // output tile
constexpr int RAD = 3;               // candidate window half-width
constexpr int GROWS = 38;            // staged rows: y0-3 .. y0+34
constexpr int QXQ = 10;              // float4-quads per staged row (40 cols)
constexpr int NQUAD = QXQ * GROWS;   // 380
constexpr int NCELL2 = 38 * 41 + 19; // 1577 (alternating 41/42 stride)

constexpr int NTILE_X = W / TX;      // 30
constexpr int NTILE = NTILE_X * (H / TY);  // 480 per batch
constexpr int BUCKET_CAP = 64;       // entries per tile bucket (mean ~5.5)

__device__ __forceinline__ int rowOff(int r) { return r * 41 + (r >> 1); }

struct alignas(8) HPack { __half2 a; __half2 b; };   // (f0,f1),(f2,f3)

// ---- prepass: corners escaping the +-RAD box -> per-tile bucket lists
__global__ __launch_bounds__(256) void outlier_pass(
    const float* __restrict__ frame,
    const float* __restrict__ flow,
    const float* __restrict__ imp,
    int* __restrict__ bcnt,          // [B*NTILE]
    float* __restrict__ bucket)      // [B*NTILE * BUCKET_CAP * 8]
{
    int g = blockIdx.x * blockDim.x + threadIdx.x;
    if (g >= NPIX / 4) return;
    const int QHW = HW / 4;
    int b = g / QHW;
    int q = g - b * QHW;
    int p0 = q * 4;
    int sy = p0 / W;
    int sx0 = p0 - sy * W;            // W%4==0 -> quad within one row

    const size_t flb = (size_t)b * 2 * HW;
    float4 vfx = *(const float4*)(flow + flb + p0);
    float4 vfy = *(const float4*)(flow + flb + HW + p0);
    float aflx[4] = {vfx.x, vfx.y, vfx.z, vfx.w};
    float afly[4] = {vfy.x, vfy.y, vfy.z, vfy.w};

    const size_t fb = (size_t)b * CHW;
    const size_t ib = (size_t)b * HW;

    #pragma unroll
    for (int k = 0; k < 4; ++k) {
        float flx = aflx[k];
        float fly = afly[k];
        // |fl| <= RAD-1 guarantees both corners within +-RAD box
        if (fabsf(flx) <= (float)(RAD - 1) && fabsf(fly) <= (float)(RAD - 1)) continue;

        int sx = sx0 + k;
        int p = p0 + k;
        float tx = (float)sx + flx;
        float ty = (float)sy + fly;
        float fxf = floorf(tx);
        float fyf = floorf(ty);
        float dx = tx - fxf;
        float dy = ty - fyf;
        int fx = (int)fxf;
        int fy = (int)fyf;

        float im = __expf(imp[ib + p]);
        float f0 = frame[fb + 0 * HW + p] * im;
        float f1 = frame[fb + 1 * HW + p] * im;
        float f2 = frame[fb + 2 * HW + p] * im;
        float f3 = frame[fb + 3 * HW + p] * im;

        #pragma unroll
        for (int cyi = 0; cyi < 2; ++cyi) {
            #pragma unroll
            for (int cxi = 0; cxi < 2; ++cxi) {
                int cx = fx + cxi;
                int cy = fy + cyi;
                if ((unsigned)cx >= (unsigned)W || (unsigned)cy >= (unsigned)H) continue;
                int ax = cx - sx; if (ax < 0) ax = -ax;
                int ay = cy - sy; if (ay < 0) ay = -ay;
                if (ax <= RAD && ay <= RAD) continue;   // covered by owner's gather
                float w = (cxi ? dx : 1.0f - dx) * (cyi ? dy : 1.0f - dy);
                int tile = b * NTILE + (cy >> 5) * NTILE_X + (cx >> 5);
                int e = atomicAdd(&bcnt[tile], 1);
                if (e < BUCKET_CAP) {
                    float* ent = bucket + ((size_t)tile * BUCKET_CAP + e) * 8;
                    ent[0] = __int_as_float((cy & 31) * TX + (cx & 31));
                    ent[1] = f0 * w;
                    ent[2] = f1 * w;
                    ent[3] = f2 * w;
                    ent[4] = f3 * w;
                    ent[5] = im * w;
                }
            }
        }
    }
}

// ---- main: stage region, 2x2-quad packed-f32 gather, bucket merge, store
__global__ __launch_bounds__(256) void splat_gather(
    const float* __restrict__ frame,
    const float* __restrict__ flow,
    const float* __restrict__ imp,
    float* __restrict__ out,
    const int* __restrict__ bcnt,
    const float* __restrict__ bucket)
{
    // 30.8 KB -> 5 blocks/CU. Partitioned; aliased by the bucket merge.
    __shared__ float smem[5 * NCELL2];             // 7885 floats
    float2* XY = (float2*)smem;                    // (tx, ty) f32
    float*  IM = smem + 2 * NCELL2;                // im f32
    HPack*  CH = (HPack*)(smem + 3 * NCELL2);      // f0..f3 f16

    const int tid = threadIdx.x;
    const int x0 = blockIdx.x * TX;
    const int y0 = blockIdx.y * TY;
    const int b  = blockIdx.z;

    const float* fxp   = flow + (size_t)b * 2 * HW;
    const float* fyp   = fxp + HW;
    const float* imp_p = imp + (size_t)b * HW;
    const float* c0p   = frame + (size_t)b * CHW;
    const float* c1p   = c0p + HW;
    const float* c2p   = c1p + HW;
    const float* c3p   = c2p + HW;

    // ---------- stage 40x38 region, premultiplied, absolute target coords
    #pragma unroll
    for (int it = 0; it < 2; ++it) {
        int q = tid + it * 256;
        if (q < NQUAD) {
            int r = q / QXQ;
            int c = q - r * QXQ;
            int sy = y0 - RAD + r;          // rows y0-3 .. y0+34
            int sx0 = x0 - 4 + 4 * c;       // cols x0-4 .. x0+35 (16B aligned)
            int p = sy * W + sx0;
            int pc = p < 0 ? 0 : (p > HW - 4 ? HW - 4 : p);
            bool qv = ((unsigned)sy < (unsigned)H) & ((unsigned)sx0 < (unsigned)W);

            float4 vfx = *(const float4*)(fxp + pc);
            float4 vfy = *(const float4*)(fyp + pc);
            float4 vim = *(const float4*)(imp_p + pc);
            float4 v0  = *(const float4*)(c0p + pc);
            float4 v1  = *(const float4*)(c1p + pc);
            float4 v2  = *(const float4*)(c2p + pc);
            float4 v3  = *(const float4*)(c3p + pc);

            float aflx[4] = {vfx.x, vfx.y, vfx.z, vfx.w};
            float afly[4] = {vfy.x, vfy.y, vfy.z, vfy.w};
            float aim [4] = {vim.x, vim.y, vim.z, vim.w};
            float a0  [4] = {v0.x,  v0.y,  v0.z,  v0.w};
            float a1  [4] = {v1.x,  v1.y,  v1.z,  v1.w};
            float a2  [4] = {v2.x,  v2.y,  v2.z,  v2.w};
            float a3  [4] = {v3.x,  v3.y,  v3.z,  v3.w};

            int base = rowOff(r) + c * 4;
            #pragma unroll
            for (int k = 0; k < 4; ++k) {
                float im = qv ? __expf(aim[k]) : 0.0f;   // im=0 kills invalid cells
                float txv = (float)(sx0 + k) + aflx[k];
                float tyv = (float)sy + afly[k];
                XY[base + k] = make_float2(txv, tyv);
                IM[base + k] = im;
                HPack hp;
                hp.a = __floats2half2_rn(a0[k] * im, a1[k] * im);
                hp.b = __floats2half2_rn(a2[k] * im, a3[k] * im);
                CH[base + k] = hp;
            }
        }
    }
    __syncthreads();

    // ---------- 2x2 quad register gather (packed f32 accumulate)
    const int qx = tid & 15;
    const int qy = tid >> 4;
    const float ox0f = (float)(x0 + 2 * qx);
    const float oy0f = (float)(y0 + 2 * qy);

    // pairs: *A = output row k=0 (cols j=0,1), *B = row k=1
    f32x2 accwA = {0.f, 0.f}, accwB = {0.f, 0.f};
    f32x2 acc0A = {0.f, 0.f}, acc0B = {0.f, 0.f};
    f32x2 acc1A = {0.f, 0.f}, acc1B = {0.f, 0.f};
    f32x2 acc2A = {0.f, 0.f}, acc2B = {0.f, 0.f};
    f32x2 acc3A = {0.f, 0.f}, acc3B = {0.f, 0.f};

    for (int dyi = 0; dyi < 8; ++dyi) {
        int r = 2 * qy + dyi;
        int ro = rowOff(r) + 2 * qx + 1;
        #pragma unroll
        for (int dxi = 0; dxi < 8; ++dxi) {
            float2 xy = XY[ro + dxi];
            float ddy = xy.y - oy0f;
            float wy0 = (dyi <= 6) ? fmaxf(0.0f, 1.0f - fabsf(ddy))        : 0.0f;
            float wy1 = (dyi >= 1) ? fmaxf(0.0f, 1.0f - fabsf(ddy - 1.0f)) : 0.0f;
            if (wy0 + wy1 > 0.0f) {
                float ddx = xy.x - ox0f;
                float wx0 = (dxi <= 6) ? fmaxf(0.0f, 1.0f - fabsf(ddx))        : 0.0f;
                float wx1 = (dxi >= 1) ? fmaxf(0.0f, 1.0f - fabsf(ddx - 1.0f)) : 0.0f;
                f32x2 wxv = {wx0, wx1};
                f32x2 t0 = wy0 * wxv;          // v_pk_mul_f32
                f32x2 t1 = wy1 * wxv;
                if ((t0.x + t0.y) + (t1.x + t1.y) > 0.0f) {   // any-hit
                    float imv = IM[ro + dxi];
                    HPack hp = CH[ro + dxi];
                    float2 f01 = __half22float2(hp.a);
                    float2 f23 = __half22float2(hp.b);
                    f32x2 s;
                    s = (f32x2){imv, imv};
                    accwA = __builtin_elementwise_fma(s, t0, accwA);
                    accwB = __builtin_elementwise_fma(s, t1, accwB);
                    s = (f32x2){f01.x, f01.x};
                    acc0A = __builtin_elementwise_fma(s, t0, acc0A);
                    acc0B = __builtin_elementwise_fma(s, t1, acc0B);
                    s = (f32x2){f01.y, f01.y};
                    acc1A = __builtin_elementwise_fma(s, t0, acc1A);
                    acc1B = __builtin_elementwise_fma(s, t1, acc1B);
                    s = (f32x2){f23.x, f23.x};
                    acc2A = __builtin_elementwise_fma(s, t0, acc2A);
                    acc2B = __builtin_elementwise_fma(s, t1, acc2B);
                    s = (f32x2){f23.y, f23.y};
                    acc3A = __builtin_elementwise_fma(s, t0, acc3A);
                    acc3B = __builtin_elementwise_fma(s, t1, acc3B);
                }
            }
        }
    }

    // ---------- per-tile bucket merge (mean ~6 entries; aliases smem)
    __syncthreads();
    const int tile = b * NTILE + blockIdx.y * NTILE_X + blockIdx.x;
    int cnt = bcnt[tile];
    if (cnt > BUCKET_CAP) cnt = BUCKET_CAP;
    if (cnt > 0) {                                     // uniform branch
        float* oacc = smem;                            // 5*1024 floats
        for (int i = tid; i < 5 * 1024; i += 256) oacc[i] = 0.0f;
        __syncthreads();
        const float* bb = bucket + (size_t)tile * BUCKET_CAP * 8;
        for (int e = tid; e < cnt; e += 256) {
            const float* ent = bb + (size_t)e * 8;
            int cell = __float_as_int(ent[0]);
            atomicAdd(&oacc[0 * 1024 + cell], ent[1]);
            atomicAdd(&oacc[1 * 1024 + cell], ent[2]);
            atomicAdd(&oacc[2 * 1024 + cell], ent[3]);
            atomicAdd(&oacc[3 * 1024 + cell], ent[4]);
            atomicAdd(&oacc[4 * 1024 + cell], ent[5]);
        }
        __syncthreads();
        int c00 = (2 * qy) * TX + 2 * qx;
        int c10 = c00 + TX;
        acc0A.x += oacc[0 * 1024 + c00];  acc0A.y += oacc[0 * 1024 + c00 + 1];
        acc0B.x += oacc[0 * 1024 + c10];  acc0B.y += oacc[0 * 1024 + c10 + 1];
        acc1A.x += oacc[1 * 1024 + c00];  acc1A.y += oacc[1 * 1024 + c00 + 1];
        acc1B.x += oacc[1 * 1024 + c10];  acc1B.y += oacc[1 * 1024 + c10 + 1];
        acc2A.x += oacc[2 * 1024 + c00];  acc2A.y += oacc[2 * 1024 + c00 + 1];
        acc2B.x += oacc[2 * 1024 + c10];  acc2B.y += oacc[2 * 1024 + c10 + 1];
        acc3A.x += oacc[3 * 1024 + c00];  acc3A.y += oacc[3 * 1024 + c00 + 1];
        acc3B.x += oacc[3 * 1024 + c10];  acc3B.y += oacc[3 * 1024 + c10 + 1];
        accwA.x += oacc[4 * 1024 + c00];  accwA.y += oacc[4 * 1024 + c00 + 1];
        accwB.x += oacc[4 * 1024 + c10];  accwB.y += oacc[4 * 1024 + c10 + 1];
    }

    // ---------- fused normalize + float2 stores (lanes qx-consecutive)
    float i00 = 1.0f / (accwA.x + EPS);
    float i01 = 1.0f / (accwA.y + EPS);
    float i10 = 1.0f / (accwB.x + EPS);
    float i11 = 1.0f / (accwB.y + EPS);

    size_t ob0 = (size_t)b * CHW + (size_t)(y0 + 2 * qy) * W + (x0 + 2 * qx);
    size_t ob1 = ob0 + W;
    *(float2*)(out + ob0 + 0 * HW) = make_float2(acc0A.x * i00, acc0A.y * i01);
    *(float2*)(out + ob0 + 1 * HW) = make_float2(acc1A.x * i00, acc1A.y * i01);
    *(float2*)(out + ob0 + 2 * HW) = make_float2(acc2A.x * i00, acc2A.y * i01);
    *(float2*)(out + ob0 + 3 * HW) = make_float2(acc3A.x * i00, acc3A.y * i01);
    *(float2*)(out + ob1 + 0 * HW) = make_float2(acc0B.x * i10, acc0B.y * i11);
    *(float2*)(out + ob1 + 1 * HW) = make_float2(acc1B.x * i10, acc1B.y * i11);
    *(float2*)(out + ob1 + 2 * HW) = make_float2(acc2B.x * i10, acc2B.y * i11);
    *(float2*)(out + ob1 + 3 * HW) = make_float2(acc3B.x * i10, acc3B.y * i11);
}

extern "C" void kernel_launch(void* const* d_in, const int* in_sizes, int n_in,
                              void* d_out, int out_size, void* d_ws, size_t ws_size,
                              hipStream_t stream) {
    const float* frame = (const float*)d_in[0];
    const float* flow  = (const float*)d_in[1];
    const float* imp   = (const float*)d_in[2];
    float* out = (float*)d_out;

    int*   bcnt   = (int*)d_ws;                         // 3840 * 4 B
    float* bucket = (float*)((char*)d_ws + 16384);      // 3840*64*32 B = 7.9 MB

    hipMemsetAsync(bcnt, 0, B * NTILE * sizeof(int), stream);

    outlier_pass<<<(NPIX / 4 + 255) / 256, 256, 0, stream>>>(frame, flow, imp, bcnt, bucket);

    dim3 grid(W / TX, H / TY, B);   // 30 x 16 x 8
    splat_gather<<<grid, 256, 0, stream>>>(frame, flow, imp, out, bcnt, bucket);
}

// Round 18
// 114.053 us; speedup vs baseline: 1.0033x; 1.0033x over previous
//
#include <hip/hip_runtime.h>
#include <hip/hip_fp16.h>
#include <math.h>

// Softmax splatting: B=8, C=4, H=512, W=960, fp32.
// R18: R16's proven scalar-fma 2x2-quad gather + R17's proven alternating
// row stride (41/42 -> two-row stride 166 dwords == 6 mod 32, kills the
// 4-way b64 bank conflict). f32x2 pk experiment reverted (R17: compiler
// emitted scalar fma + extra moves).
// Numerics frozen: flow f32, im f32, abs coords, channels f16, runtime dyi.

#define EPS 1e-7f

constexpr int B = 8, C = 4, H = 512, W = 960;
constexpr int HW = H * W;            // 491520
constexpr int CHW = C * HW;          // 1966080
constexpr int NPIX = B * HW;         // 3932160

constexpr int TX = 32, TY = 32;      // output tile
constexpr int RAD = 3;               // candidate window half-width
constexpr int GROWS = 38;            // staged rows: y0-3 .. y0+34
constexpr int QXQ = 10;              // float4-quads per staged row (40 cols)
constexpr int NQUAD = QXQ * GROWS;   // 380
constexpr int NCELL2 = 38 * 41 + 19; // 1577 (alternating 41/42 stride)

constexpr int NTILE_X = W / TX;      // 30
constexpr int NTILE = NTILE_X * (H / TY);  // 480 per batch
constexpr int BUCKET_CAP = 64;       // entries per tile bucket (mean ~5.5)

__device__ __forceinline__ int rowOff(int r) { return r * 41 + (r >> 1); }

struct alignas(8) HPack { __half2 a; __half2 b; };   // (f0,f1),(f2,f3)

// ---- prepass: corners escaping the +-RAD box -> per-tile bucket lists
__global__ __launch_bounds__(256) void outlier_pass(
    const float* __restrict__ frame,
    const float* __restrict__ flow,
    const float* __restrict__ imp,
    int* __restrict__ bcnt,          // [B*NTILE]
    float* __restrict__ bucket)      // [B*NTILE * BUCKET_CAP * 8]
{
    int g = blockIdx.x * blockDim.x + threadIdx.x;
    if (g >= NPIX / 4) return;
    const int QHW = HW / 4;
    int b = g / QHW;
    int q = g - b * QHW;
    int p0 = q * 4;
    int sy = p0 / W;
    int sx0 = p0 - sy * W;            // W%4==0 -> quad within one row

    const size_t flb = (size_t)b * 2 * HW;
    float4 vfx = *(const float4*)(flow + flb + p0);
    float4 vfy = *(const float4*)(flow + flb + HW + p0);
    float aflx[4] = {vfx.x, vfx.y, vfx.z, vfx.w};
    float afly[4] = {vfy.x, vfy.y, vfy.z, vfy.w};

    const size_t fb = (size_t)b * CHW;
    const size_t ib = (size_t)b * HW;

    #pragma unroll
    for (int k = 0; k < 4; ++k) {
        float flx = aflx[k];
        float fly = afly[k];
        // |fl| <= RAD-1 guarantees both corners within +-RAD box
        if (fabsf(flx) <= (float)(RAD - 1) && fabsf(fly) <= (float)(RAD - 1)) continue;

        int sx = sx0 + k;
        int p = p0 + k;
        float tx = (float)sx + flx;
        float ty = (float)sy + fly;
        float fxf = floorf(tx);
        float fyf = floorf(ty);
        float dx = tx - fxf;
        float dy = ty - fyf;
        int fx = (int)fxf;
        int fy = (int)fyf;

        float im = __expf(imp[ib + p]);
        float f0 = frame[fb + 0 * HW + p] * im;
        float f1 = frame[fb + 1 * HW + p] * im;
        float f2 = frame[fb + 2 * HW + p] * im;
        float f3 = frame[fb + 3 * HW + p] * im;

        #pragma unroll
        for (int cyi = 0; cyi < 2; ++cyi) {
            #pragma unroll
            for (int cxi = 0; cxi < 2; ++cxi) {
                int cx = fx + cxi;
                int cy = fy + cyi;
                if ((unsigned)cx >= (unsigned)W || (unsigned)cy >= (unsigned)H) continue;
                int ax = cx - sx; if (ax < 0) ax = -ax;
                int ay = cy - sy; if (ay < 0) ay = -ay;
                if (ax <= RAD && ay <= RAD) continue;   // covered by owner's gather
                float w = (cxi ? dx : 1.0f - dx) * (cyi ? dy : 1.0f - dy);
                int tile = b * NTILE + (cy >> 5) * NTILE_X + (cx >> 5);
                int e = atomicAdd(&bcnt[tile], 1);
                if (e < BUCKET_CAP) {
                    float* ent = bucket + ((size_t)tile * BUCKET_CAP + e) * 8;
                    ent[0] = __int_as_float((cy & 31) * TX + (cx & 31));
                    ent[1] = f0 * w;
                    ent[2] = f1 * w;
                    ent[3] = f2 * w;
                    ent[4] = f3 * w;
                    ent[5] = im * w;
                }
            }
        }
    }
}

// ---- main: stage region, 2x2-quad register gather, bucket merge, store
__global__ __launch_bounds__(256) void splat_gather(
    const float* __restrict__ frame,
    const float* __restrict__ flow,
    const float* __restrict__ imp,
    float* __restrict__ out,
    const int* __restrict__ bcnt,
    const float* __restrict__ bucket)
{
    // 30.8 KB -> 5 blocks/CU. Partitioned; aliased by the bucket merge.
    __shared__ float smem[5 * NCELL2];             // 7885 floats
    float2* XY = (float2*)smem;                    // (tx, ty) f32
    float*  IM = smem + 2 * NCELL2;                // im f32
    HPack*  CH = (HPack*)(smem + 3 * NCELL2);      // f0..f3 f16

    const int tid = threadIdx.x;
    const int x0 = blockIdx.x * TX;
    const int y0 = blockIdx.y * TY;
    const int b  = blockIdx.z;

    const float* fxp   = flow + (size_t)b * 2 * HW;
    const float* fyp   = fxp + HW;
    const float* imp_p = imp + (size_t)b * HW;
    const float* c0p   = frame + (size_t)b * CHW;
    const float* c1p   = c0p + HW;
    const float* c2p   = c1p + HW;
    const float* c3p   = c2p + HW;

    // ---------- stage 40x38 region, premultiplied, absolute target coords
    #pragma unroll
    for (int it = 0; it < 2; ++it) {
        int q = tid + it * 256;
        if (q < NQUAD) {
            int r = q / QXQ;
            int c = q - r * QXQ;
            int sy = y0 - RAD + r;          // rows y0-3 .. y0+34
            int sx0 = x0 - 4 + 4 * c;       // cols x0-4 .. x0+35 (16B aligned)
            int p = sy * W + sx0;
            int pc = p < 0 ? 0 : (p > HW - 4 ? HW - 4 : p);
            bool qv = ((unsigned)sy < (unsigned)H) & ((unsigned)sx0 < (unsigned)W);

            float4 vfx = *(const float4*)(fxp + pc);
            float4 vfy = *(const float4*)(fyp + pc);
            float4 vim = *(const float4*)(imp_p + pc);
            float4 v0  = *(const float4*)(c0p + pc);
            float4 v1  = *(const float4*)(c1p + pc);
            float4 v2  = *(const float4*)(c2p + pc);
            float4 v3  = *(const float4*)(c3p + pc);

            float aflx[4] = {vfx.x, vfx.y, vfx.z, vfx.w};
            float afly[4] = {vfy.x, vfy.y, vfy.z, vfy.w};
            float aim [4] = {vim.x, vim.y, vim.z, vim.w};
            float a0  [4] = {v0.x,  v0.y,  v0.z,  v0.w};
            float a1  [4] = {v1.x,  v1.y,  v1.z,  v1.w};
            float a2  [4] = {v2.x,  v2.y,  v2.z,  v2.w};
            float a3  [4] = {v3.x,  v3.y,  v3.z,  v3.w};

            int base = rowOff(r) + c * 4;
            #pragma unroll
            for (int k = 0; k < 4; ++k) {
                float im = qv ? __expf(aim[k]) : 0.0f;   // im=0 kills invalid cells
                float txv = (float)(sx0 + k) + aflx[k];
                float tyv = (float)sy + afly[k];
                XY[base + k] = make_float2(txv, tyv);
                IM[base + k] = im;
                HPack hp;
                hp.a = __floats2half2_rn(a0[k] * im, a1[k] * im);
                hp.b = __floats2half2_rn(a2[k] * im, a3[k] * im);
                CH[base + k] = hp;
            }
        }
    }
    __syncthreads();

    // ---------- 2x2 quad register gather: thread owns rows {2qy,2qy+1},
    //            cols {2qx, 2qx+1} of the tile
    const int qx = tid & 15;
    const int qy = tid >> 4;
    const float ox0f = (float)(x0 + 2 * qx);
    const float oy0f = (float)(y0 + 2 * qy);

    float accw[4] = {0.f, 0.f, 0.f, 0.f};
    float acc0[4] = {0.f, 0.f, 0.f, 0.f};
    float acc1[4] = {0.f, 0.f, 0.f, 0.f};
    float acc2[4] = {0.f, 0.f, 0.f, 0.f};
    float acc3[4] = {0.f, 0.f, 0.f, 0.f};

    // staged row r = 2qy + dyi; staged col c = 2qx + 1 + dxi
    for (int dyi = 0; dyi < 8; ++dyi) {
        int rowoff = rowOff(2 * qy + dyi) + 2 * qx + 1;
        #pragma unroll
        for (int dxi = 0; dxi < 8; ++dxi) {
            float2 xy = XY[rowoff + dxi];
            float ddy = xy.y - oy0f;
            float wy0 = (dyi <= 6) ? fmaxf(0.0f, 1.0f - fabsf(ddy))        : 0.0f;
            float wy1 = (dyi >= 1) ? fmaxf(0.0f, 1.0f - fabsf(ddy - 1.0f)) : 0.0f;
            if (wy0 + wy1 > 0.0f) {
                float ddx = xy.x - ox0f;
                float wx0 = (dxi <= 6) ? fmaxf(0.0f, 1.0f - fabsf(ddx))        : 0.0f;
                float wx1 = (dxi >= 1) ? fmaxf(0.0f, 1.0f - fabsf(ddx - 1.0f)) : 0.0f;
                float t00 = wy0 * wx0, t01 = wy0 * wx1;
                float t10 = wy1 * wx0, t11 = wy1 * wx1;
                if ((t00 + t01) + (t10 + t11) > 0.0f) {   // any-hit
                    float im = IM[rowoff + dxi];
                    HPack hp = CH[rowoff + dxi];
                    float2 f01 = __half22float2(hp.a);
                    float2 f23 = __half22float2(hp.b);
                    accw[0] = fmaf(im, t00, accw[0]);
                    accw[1] = fmaf(im, t01, accw[1]);
                    accw[2] = fmaf(im, t10, accw[2]);
                    accw[3] = fmaf(im, t11, accw[3]);
                    acc0[0] = fmaf(f01.x, t00, acc0[0]);
                    acc0[1] = fmaf(f01.x, t01, acc0[1]);
                    acc0[2] = fmaf(f01.x, t10, acc0[2]);
                    acc0[3] = fmaf(f01.x, t11, acc0[3]);
                    acc1[0] = fmaf(f01.y, t00, acc1[0]);
                    acc1[1] = fmaf(f01.y, t01, acc1[1]);
                    acc1[2] = fmaf(f01.y, t10, acc1[2]);
                    acc1[3] = fmaf(f01.y, t11, acc1[3]);
                    acc2[0] = fmaf(f23.x, t00, acc2[0]);
                    acc2[1] = fmaf(f23.x, t01, acc2[1]);
                    acc2[2] = fmaf(f23.x, t10, acc2[2]);
                    acc2[3] = fmaf(f23.x, t11, acc2[3]);
                    acc3[0] = fmaf(f23.y, t00, acc3[0]);
                    acc3[1] = fmaf(f23.y, t01, acc3[1]);
                    acc3[2] = fmaf(f23.y, t10, acc3[2]);
                    acc3[3] = fmaf(f23.y, t11, acc3[3]);
                }
            }
        }
    }

    // ---------- per-tile bucket merge (mean ~6 entries; aliases smem)
    __syncthreads();
    const int tile = b * NTILE + blockIdx.y * NTILE_X + blockIdx.x;
    int cnt = bcnt[tile];
    if (cnt > BUCKET_CAP) cnt = BUCKET_CAP;
    if (cnt > 0) {                                     // uniform branch
        float* oacc = smem;                            // 5*1024 floats
        for (int i = tid; i < 5 * 1024; i += 256) oacc[i] = 0.0f;
        __syncthreads();
        const float* bb = bucket + (size_t)tile * BUCKET_CAP * 8;
        for (int e = tid; e < cnt; e += 256) {
            const float* ent = bb + (size_t)e * 8;
            int cell = __float_as_int(ent[0]);
            atomicAdd(&oacc[0 * 1024 + cell], ent[1]);
            atomicAdd(&oacc[1 * 1024 + cell], ent[2]);
            atomicAdd(&oacc[2 * 1024 + cell], ent[3]);
            atomicAdd(&oacc[3 * 1024 + cell], ent[4]);
            atomicAdd(&oacc[4 * 1024 + cell], ent[5]);
        }
        __syncthreads();
        #pragma unroll
        for (int k = 0; k < 2; ++k) {
            #pragma unroll
            for (int j = 0; j < 2; ++j) {
                int cell = (2 * qy + k) * TX + 2 * qx + j;
                int a = k * 2 + j;
                acc0[a] += oacc[0 * 1024 + cell];
                acc1[a] += oacc[1 * 1024 + cell];
                acc2[a] += oacc[2 * 1024 + cell];
                acc3[a] += oacc[3 * 1024 + cell];
                accw[a] += oacc[4 * 1024 + cell];
            }
        }
    }

    // ---------- fused normalize + float2 stores (lanes qx-consecutive)
    float inv[4];
    #pragma unroll
    for (int a = 0; a < 4; ++a) inv[a] = 1.0f / (accw[a] + EPS);

    #pragma unroll
    for (int k = 0; k < 2; ++k) {
        size_t obase = (size_t)b * CHW + (size_t)(y0 + 2 * qy + k) * W + (x0 + 2 * qx);
        int a0i = k * 2, a1i = k * 2 + 1;
        *(float2*)(out + obase + 0 * HW) = make_float2(acc0[a0i] * inv[a0i], acc0[a1i] * inv[a1i]);
        *(float2*)(out + obase + 1 * HW) = make_float2(acc1[a0i] * inv[a0i], acc1[a1i] * inv[a1i]);
        *(float2*)(out + obase + 2 * HW) = make_float2(acc2[a0i] * inv[a0i], acc2[a1i] * inv[a1i]);
        *(float2*)(out + obase + 3 * HW) = make_float2(acc3[a0i] * inv[a0i], acc3[a1i] * inv[a1i]);
    }
}

extern "C" void kernel_launch(void* const* d_in, const int* in_sizes, int n_in,
                              void* d_out, int out_size, void* d_ws, size_t ws_size,
                              hipStream_t stream) {
    const float* frame = (const float*)d_in[0];
    const float* flow  = (const float*)d_in[1];
    const float* imp   = (const float*)d_in[2];
    float* out = (float*)d_out;

    int*   bcnt   = (int*)d_ws;                         // 3840 * 4 B
    float* bucket = (float*)((char*)d_ws + 16384);      // 3840*64*32 B = 7.9 MB

    hipMemsetAsync(bcnt, 0, B * NTILE * sizeof(int), stream);

    outlier_pass<<<(NPIX / 4 + 255) / 256, 256, 0, stream>>>(frame, flow, imp, bcnt, bucket);

    dim3 grid(W / TX, H / TY, B);   // 30 x 16 x 8
    splat_gather<<<grid, 256, 0, stream>>>(frame, flow, imp, out, bcnt, bucket);
}

// Round 19
// 109.032 us; speedup vs baseline: 1.0495x; 1.0460x over previous
//
#include <hip/hip_runtime.h>
#include <hip/hip_fp16.h>
#include <math.h>

// Softmax splatting: B=8, C=4, H=512, W=960, fp32.
// R19: exact R16 structure (proven 83 us splat_gather) with ONE change:
// LSTRIDE 41 -> 42. Two-row stride = 168 dwords == 8 mod 32 -> the four
// qy lane-groups' b64 reads tile the banks at 2-way overlap (free, m136),
// vs stride 41's 82==18 with 3-way hot banks. No rowOff address math
// (R17/R18 showed rowOff cost ~6 us despite fewer counted conflicts).
// Numerics frozen: flow f32, im f32, abs coords, channels f16, runtime dyi.

#define EPS 1e-7f

constexpr int B = 8, C = 4, H = 512, W = 960;
constexpr int HW = H * W;            // 491520
constexpr int CHW = C * HW;          // 1966080
constexpr int NPIX = B * HW;         // 3932160

constexpr int TX = 32, TY = 32;      // output tile
constexpr int RAD = 3;               // candidate window half-width
constexpr int GROWS = 38;            // staged rows: y0-3 .. y0+34
constexpr int QXQ = 10;              // float4-quads per staged row (40 cols)
constexpr int NQUAD = QXQ * GROWS;   // 380
constexpr int LSTRIDE = 42;          // cell stride per row (uniform; 2-row = 8 mod 32)
constexpr int NCELL = GROWS * LSTRIDE;  // 1596

constexpr int NTILE_X = W / TX;      // 30
constexpr int NTILE = NTILE_X * (H / TY);  // 480 per batch
constexpr int BUCKET_CAP = 64;       // entries per tile bucket (mean ~5.5)

struct alignas(8) HPack { __half2 a; __half2 b; };   // (f0,f1),(f2,f3)

// ---- prepass: corners escaping the +-RAD box -> per-tile bucket lists
__global__ __launch_bounds__(256) void outlier_pass(
    const float* __restrict__ frame,
    const float* __restrict__ flow,
    const float* __restrict__ imp,
    int* __restrict__ bcnt,          // [B*NTILE]
    float* __restrict__ bucket)      // [B*NTILE * BUCKET_CAP * 8]
{
    int g = blockIdx.x * blockDim.x + threadIdx.x;
    if (g >= NPIX / 4) return;
    const int QHW = HW / 4;
    int b = g / QHW;
    int q = g - b * QHW;
    int p0 = q * 4;
    int sy = p0 / W;
    int sx0 = p0 - sy * W;            // W%4==0 -> quad within one row

    const size_t flb = (size_t)b * 2 * HW;
    float4 vfx = *(const float4*)(flow + flb + p0);
    float4 vfy = *(const float4*)(flow + flb + HW + p0);
    float aflx[4] = {vfx.x, vfx.y, vfx.z, vfx.w};
    float afly[4] = {vfy.x, vfy.y, vfy.z, vfy.w};

    const size_t fb = (size_t)b * CHW;
    const size_t ib = (size_t)b * HW;

    #pragma unroll
    for (int k = 0; k < 4; ++k) {
        float flx = aflx[k];
        float fly = afly[k];
        // |fl| <= RAD-1 guarantees both corners within +-RAD box
        if (fabsf(flx) <= (float)(RAD - 1) && fabsf(fly) <= (float)(RAD - 1)) continue;

        int sx = sx0 + k;
        int p = p0 + k;
        float tx = (float)sx + flx;
        float ty = (float)sy + fly;
        float fxf = floorf(tx);
        float fyf = floorf(ty);
        float dx = tx - fxf;
        float dy = ty - fyf;
        int fx = (int)fxf;
        int fy = (int)fyf;

        float im = __expf(imp[ib + p]);
        float f0 = frame[fb + 0 * HW + p] * im;
        float f1 = frame[fb + 1 * HW + p] * im;
        float f2 = frame[fb + 2 * HW + p] * im;
        float f3 = frame[fb + 3 * HW + p] * im;

        #pragma unroll
        for (int cyi = 0; cyi < 2; ++cyi) {
            #pragma unroll
            for (int cxi = 0; cxi < 2; ++cxi) {
                int cx = fx + cxi;
                int cy = fy + cyi;
                if ((unsigned)cx >= (unsigned)W || (unsigned)cy >= (unsigned)H) continue;
                int ax = cx - sx; if (ax < 0) ax = -ax;
                int ay = cy - sy; if (ay < 0) ay = -ay;
                if (ax <= RAD && ay <= RAD) continue;   // covered by owner's gather
                float w = (cxi ? dx : 1.0f - dx) * (cyi ? dy : 1.0f - dy);
                int tile = b * NTILE + (cy >> 5) * NTILE_X + (cx >> 5);
                int e = atomicAdd(&bcnt[tile], 1);
                if (e < BUCKET_CAP) {
                    float* ent = bucket + ((size_t)tile * BUCKET_CAP + e) * 8;
                    ent[0] = __int_as_float((cy & 31) * TX + (cx & 31));
                    ent[1] = f0 * w;
                    ent[2] = f1 * w;
                    ent[3] = f2 * w;
                    ent[4] = f3 * w;
                    ent[5] = im * w;
                }
            }
        }
    }
}

// ---- main: stage region, 2x2-quad register gather, bucket merge, store
__global__ __launch_bounds__(256) void splat_gather(
    const float* __restrict__ frame,
    const float* __restrict__ flow,
    const float* __restrict__ imp,
    float* __restrict__ out,
    const int* __restrict__ bcnt,
    const float* __restrict__ bucket)
{
    // 31.9 KB -> 5 blocks/CU. Partitioned; aliased by the bucket merge.
    __shared__ float smem[5 * NCELL];              // 7980 floats
    float2* XY = (float2*)smem;                    // (tx, ty) f32
    float*  IM = smem + 2 * NCELL;                 // im f32
    HPack*  CH = (HPack*)(smem + 3 * NCELL);       // f0..f3 f16

    const int tid = threadIdx.x;
    const int x0 = blockIdx.x * TX;
    const int y0 = blockIdx.y * TY;
    const int b  = blockIdx.z;

    const float* fxp   = flow + (size_t)b * 2 * HW;
    const float* fyp   = fxp + HW;
    const float* imp_p = imp + (size_t)b * HW;
    const float* c0p   = frame + (size_t)b * CHW;
    const float* c1p   = c0p + HW;
    const float* c2p   = c1p + HW;
    const float* c3p   = c2p + HW;

    // ---------- stage 40x38 region, premultiplied, absolute target coords
    #pragma unroll
    for (int it = 0; it < 2; ++it) {
        int q = tid + it * 256;
        if (q < NQUAD) {
            int r = q / QXQ;
            int c = q - r * QXQ;
            int sy = y0 - RAD + r;          // rows y0-3 .. y0+34
            int sx0 = x0 - 4 + 4 * c;       // cols x0-4 .. x0+35 (16B aligned)
            int p = sy * W + sx0;
            int pc = p < 0 ? 0 : (p > HW - 4 ? HW - 4 : p);
            bool qv = ((unsigned)sy < (unsigned)H) & ((unsigned)sx0 < (unsigned)W);

            float4 vfx = *(const float4*)(fxp + pc);
            float4 vfy = *(const float4*)(fyp + pc);
            float4 vim = *(const float4*)(imp_p + pc);
            float4 v0  = *(const float4*)(c0p + pc);
            float4 v1  = *(const float4*)(c1p + pc);
            float4 v2  = *(const float4*)(c2p + pc);
            float4 v3  = *(const float4*)(c3p + pc);

            float aflx[4] = {vfx.x, vfx.y, vfx.z, vfx.w};
            float afly[4] = {vfy.x, vfy.y, vfy.z, vfy.w};
            float aim [4] = {vim.x, vim.y, vim.z, vim.w};
            float a0  [4] = {v0.x,  v0.y,  v0.z,  v0.w};
            float a1  [4] = {v1.x,  v1.y,  v1.z,  v1.w};
            float a2  [4] = {v2.x,  v2.y,  v2.z,  v2.w};
            float a3  [4] = {v3.x,  v3.y,  v3.z,  v3.w};

            int base = r * LSTRIDE + c * 4;
            #pragma unroll
            for (int k = 0; k < 4; ++k) {
                float im = qv ? __expf(aim[k]) : 0.0f;   // im=0 kills invalid cells
                float txv = (float)(sx0 + k) + aflx[k];
                float tyv = (float)sy + afly[k];
                XY[base + k] = make_float2(txv, tyv);
                IM[base + k] = im;
                HPack hp;
                hp.a = __floats2half2_rn(a0[k] * im, a1[k] * im);
                hp.b = __floats2half2_rn(a2[k] * im, a3[k] * im);
                CH[base + k] = hp;
            }
        }
    }
    __syncthreads();

    // ---------- 2x2 quad register gather: thread owns rows {2qy,2qy+1},
    //            cols {2qx, 2qx+1} of the tile
    const int qx = tid & 15;
    const int qy = tid >> 4;
    const float ox0f = (float)(x0 + 2 * qx);
    const float oy0f = (float)(y0 + 2 * qy);

    float accw[4] = {0.f, 0.f, 0.f, 0.f};
    float acc0[4] = {0.f, 0.f, 0.f, 0.f};
    float acc1[4] = {0.f, 0.f, 0.f, 0.f};
    float acc2[4] = {0.f, 0.f, 0.f, 0.f};
    float acc3[4] = {0.f, 0.f, 0.f, 0.f};

    // staged row r = 2qy + dyi; staged col c = 2qx + 1 + dxi
    for (int dyi = 0; dyi < 8; ++dyi) {
        int rowoff = (2 * qy + dyi) * LSTRIDE + 2 * qx + 1;
        #pragma unroll
        for (int dxi = 0; dxi < 8; ++dxi) {
            float2 xy = XY[rowoff + dxi];
            float ddy = xy.y - oy0f;
            float wy0 = (dyi <= 6) ? fmaxf(0.0f, 1.0f - fabsf(ddy))        : 0.0f;
            float wy1 = (dyi >= 1) ? fmaxf(0.0f, 1.0f - fabsf(ddy - 1.0f)) : 0.0f;
            if (wy0 + wy1 > 0.0f) {
                float ddx = xy.x - ox0f;
                float wx0 = (dxi <= 6) ? fmaxf(0.0f, 1.0f - fabsf(ddx))        : 0.0f;
                float wx1 = (dxi >= 1) ? fmaxf(0.0f, 1.0f - fabsf(ddx - 1.0f)) : 0.0f;
                float t00 = wy0 * wx0, t01 = wy0 * wx1;
                float t10 = wy1 * wx0, t11 = wy1 * wx1;
                if ((t00 + t01) + (t10 + t11) > 0.0f) {   // any-hit
                    float im = IM[rowoff + dxi];
                    HPack hp = CH[rowoff + dxi];
                    float2 f01 = __half22float2(hp.a);
                    float2 f23 = __half22float2(hp.b);
                    accw[0] = fmaf(im, t00, accw[0]);
                    accw[1] = fmaf(im, t01, accw[1]);
                    accw[2] = fmaf(im, t10, accw[2]);
                    accw[3] = fmaf(im, t11, accw[3]);
                    acc0[0] = fmaf(f01.x, t00, acc0[0]);
                    acc0[1] = fmaf(f01.x, t01, acc0[1]);
                    acc0[2] = fmaf(f01.x, t10, acc0[2]);
                    acc0[3] = fmaf(f01.x, t11, acc0[3]);
                    acc1[0] = fmaf(f01.y, t00, acc1[0]);
                    acc1[1] = fmaf(f01.y, t01, acc1[1]);
                    acc1[2] = fmaf(f01.y, t10, acc1[2]);
                    acc1[3] = fmaf(f01.y, t11, acc1[3]);
                    acc2[0] = fmaf(f23.x, t00, acc2[0]);
                    acc2[1] = fmaf(f23.x, t01, acc2[1]);
                    acc2[2] = fmaf(f23.x, t10, acc2[2]);
                    acc2[3] = fmaf(f23.x, t11, acc2[3]);
                    acc3[0] = fmaf(f23.y, t00, acc3[0]);
                    acc3[1] = fmaf(f23.y, t01, acc3[1]);
                    acc3[2] = fmaf(f23.y, t10, acc3[2]);
                    acc3[3] = fmaf(f23.y, t11, acc3[3]);
                }
            }
        }
    }

    // ---------- per-tile bucket merge (mean ~6 entries; aliases smem)
    __syncthreads();
    const int tile = b * NTILE + blockIdx.y * NTILE_X + blockIdx.x;
    int cnt = bcnt[tile];
    if (cnt > BUCKET_CAP) cnt = BUCKET_CAP;
    if (cnt > 0) {                                     // uniform branch
        float* oacc = smem;                            // 5*1024 floats
        for (int i = tid; i < 5 * 1024; i += 256) oacc[i] = 0.0f;
        __syncthreads();
        const float* bb = bucket + (size_t)tile * BUCKET_CAP * 8;
        for (int e = tid; e < cnt; e += 256) {
            const float* ent = bb + (size_t)e * 8;
            int cell = __float_as_int(ent[0]);
            atomicAdd(&oacc[0 * 1024 + cell], ent[1]);
            atomicAdd(&oacc[1 * 1024 + cell], ent[2]);
            atomicAdd(&oacc[2 * 1024 + cell], ent[3]);
            atomicAdd(&oacc[3 * 1024 + cell], ent[4]);
            atomicAdd(&oacc[4 * 1024 + cell], ent[5]);
        }
        __syncthreads();
        #pragma unroll
        for (int k = 0; k < 2; ++k) {
            #pragma unroll
            for (int j = 0; j < 2; ++j) {
                int cell = (2 * qy + k) * TX + 2 * qx + j;
                int a = k * 2 + j;
                acc0[a] += oacc[0 * 1024 + cell];
                acc1[a] += oacc[1 * 1024 + cell];
                acc2[a] += oacc[2 * 1024 + cell];
                acc3[a] += oacc[3 * 1024 + cell];
                accw[a] += oacc[4 * 1024 + cell];
            }
        }
    }

    // ---------- fused normalize + float2 stores (lanes qx-consecutive)
    float inv[4];
    #pragma unroll
    for (int a = 0; a < 4; ++a) inv[a] = 1.0f / (accw[a] + EPS);

    #pragma unroll
    for (int k = 0; k < 2; ++k) {
        size_t obase = (size_t)b * CHW + (size_t)(y0 + 2 * qy + k) * W + (x0 + 2 * qx);
        int a0i = k * 2, a1i = k * 2 + 1;
        *(float2*)(out + obase + 0 * HW) = make_float2(acc0[a0i] * inv[a0i], acc0[a1i] * inv[a1i]);
        *(float2*)(out + obase + 1 * HW) = make_float2(acc1[a0i] * inv[a0i], acc1[a1i] * inv[a1i]);
        *(float2*)(out + obase + 2 * HW) = make_float2(acc2[a0i] * inv[a0i], acc2[a1i] * inv[a1i]);
        *(float2*)(out + obase + 3 * HW) = make_float2(acc3[a0i] * inv[a0i], acc3[a1i] * inv[a1i]);
    }
}

extern "C" void kernel_launch(void* const* d_in, const int* in_sizes, int n_in,
                              void* d_out, int out_size, void* d_ws, size_t ws_size,
                              hipStream_t stream) {
    const float* frame = (const float*)d_in[0];
    const float* flow  = (const float*)d_in[1];
    const float* imp   = (const float*)d_in[2];
    float* out = (float*)d_out;

    int*   bcnt   = (int*)d_ws;                         // 3840 * 4 B
    float* bucket = (float*)((char*)d_ws + 16384);      // 3840*64*32 B = 7.9 MB

    hipMemsetAsync(bcnt, 0, B * NTILE * sizeof(int), stream);

    outlier_pass<<<(NPIX / 4 + 255) / 256, 256, 0, stream>>>(frame, flow, imp, bcnt, bucket);

    dim3 grid(W / TX, H / TY, B);   // 30 x 16 x 8
    splat_gather<<<grid, 256, 0, stream>>>(frame, flow, imp, out, bcnt, bucket);
}

// Round 20
// 107.053 us; speedup vs baseline: 1.0689x; 1.0185x over previous
//
#include <hip/hip_runtime.h>
#include <hip/hip_fp16.h>
#include <math.h>

// Softmax splatting: B=8, C=4, H=512, W=960, fp32.
// R20: R19's splat_gather (proven 83 us, VALU-issue-bound) unchanged.
// outlier_pass slimmed: bucket entries store (cell, src_idx, w, im) and the
// gather block loads the frame values itself (~6 entries/block) — removes
// the 4 scattered frame-plane reads from the ~9% slow-path pixels.

#define EPS 1e-7f

constexpr int B = 8, C = 4, H = 512, W = 960;
constexpr int HW = H * W;            // 491520
constexpr int CHW = C * HW;          // 1966080
constexpr int NPIX = B * HW;         // 3932160

constexpr int TX = 32, TY = 32;      // output tile
constexpr int RAD = 3;               // candidate window half-width
constexpr int GROWS = 38;            // staged rows: y0-3 .. y0+34
constexpr int QXQ = 10;              // float4-quads per staged row (40 cols)
constexpr int NQUAD = QXQ * GROWS;   // 380
constexpr int LSTRIDE = 42;          // cell stride per row
constexpr int NCELL = GROWS * LSTRIDE;  // 1596

constexpr int NTILE_X = W / TX;      // 30
constexpr int NTILE = NTILE_X * (H / TY);  // 480 per batch
constexpr int BUCKET_CAP = 64;       // entries per tile bucket (mean ~5.5)

struct alignas(8) HPack { __half2 a; __half2 b; };   // (f0,f1),(f2,f3)

// ---- prepass: corners escaping the +-RAD box -> per-tile bucket lists
// Slim entries: (cell, src_idx, w, im). No frame reads here.
__global__ __launch_bounds__(256) void outlier_pass(
    const float* __restrict__ flow,
    const float* __restrict__ imp,
    int* __restrict__ bcnt,          // [B*NTILE]
    float* __restrict__ bucket)      // [B*NTILE * BUCKET_CAP * 4]
{
    int g = blockIdx.x * blockDim.x + threadIdx.x;
    if (g >= NPIX / 4) return;
    const int QHW = HW / 4;
    int b = g / QHW;
    int q = g - b * QHW;
    int p0 = q * 4;
    int sy = p0 / W;
    int sx0 = p0 - sy * W;            // W%4==0 -> quad within one row

    const size_t flb = (size_t)b * 2 * HW;
    float4 vfx = *(const float4*)(flow + flb + p0);
    float4 vfy = *(const float4*)(flow + flb + HW + p0);
    float aflx[4] = {vfx.x, vfx.y, vfx.z, vfx.w};
    float afly[4] = {vfy.x, vfy.y, vfy.z, vfy.w};

    const size_t ib = (size_t)b * HW;

    #pragma unroll
    for (int k = 0; k < 4; ++k) {
        float flx = aflx[k];
        float fly = afly[k];
        // |fl| <= RAD-1 guarantees both corners within +-RAD box
        if (fabsf(flx) <= (float)(RAD - 1) && fabsf(fly) <= (float)(RAD - 1)) continue;

        int sx = sx0 + k;
        int p = p0 + k;
        float tx = (float)sx + flx;
        float ty = (float)sy + fly;
        float fxf = floorf(tx);
        float fyf = floorf(ty);
        float dx = tx - fxf;
        float dy = ty - fyf;
        int fx = (int)fxf;
        int fy = (int)fyf;

        float im = __expf(imp[ib + p]);

        #pragma unroll
        for (int cyi = 0; cyi < 2; ++cyi) {
            #pragma unroll
            for (int cxi = 0; cxi < 2; ++cxi) {
                int cx = fx + cxi;
                int cy = fy + cyi;
                if ((unsigned)cx >= (unsigned)W || (unsigned)cy >= (unsigned)H) continue;
                int ax = cx - sx; if (ax < 0) ax = -ax;
                int ay = cy - sy; if (ay < 0) ay = -ay;
                if (ax <= RAD && ay <= RAD) continue;   // covered by owner's gather
                float w = (cxi ? dx : 1.0f - dx) * (cyi ? dy : 1.0f - dy);
                int tile = b * NTILE + (cy >> 5) * NTILE_X + (cx >> 5);
                int e = atomicAdd(&bcnt[tile], 1);
                if (e < BUCKET_CAP) {
                    float* ent = bucket + ((size_t)tile * BUCKET_CAP + e) * 4;
                    ent[0] = __int_as_float((cy & 31) * TX + (cx & 31));
                    ent[1] = __int_as_float(p);
                    ent[2] = w;
                    ent[3] = im;
                }
            }
        }
    }
}

// ---- main: stage region, 2x2-quad register gather, bucket merge, store
__global__ __launch_bounds__(256) void splat_gather(
    const float* __restrict__ frame,
    const float* __restrict__ flow,
    const float* __restrict__ imp,
    float* __restrict__ out,
    const int* __restrict__ bcnt,
    const float* __restrict__ bucket)
{
    // 31.9 KB -> 5 blocks/CU. Partitioned; aliased by the bucket merge.
    __shared__ float smem[5 * NCELL];              // 7980 floats
    float2* XY = (float2*)smem;                    // (tx, ty) f32
    float*  IM = smem + 2 * NCELL;                 // im f32
    HPack*  CH = (HPack*)(smem + 3 * NCELL);       // f0..f3 f16

    const int tid = threadIdx.x;
    const int x0 = blockIdx.x * TX;
    const int y0 = blockIdx.y * TY;
    const int b  = blockIdx.z;

    const float* fxp   = flow + (size_t)b * 2 * HW;
    const float* fyp   = fxp + HW;
    const float* imp_p = imp + (size_t)b * HW;
    const float* c0p   = frame + (size_t)b * CHW;
    const float* c1p   = c0p + HW;
    const float* c2p   = c1p + HW;
    const float* c3p   = c2p + HW;

    // ---------- stage 40x38 region, premultiplied, absolute target coords
    #pragma unroll
    for (int it = 0; it < 2; ++it) {
        int q = tid + it * 256;
        if (q < NQUAD) {
            int r = q / QXQ;
            int c = q - r * QXQ;
            int sy = y0 - RAD + r;          // rows y0-3 .. y0+34
            int sx0 = x0 - 4 + 4 * c;       // cols x0-4 .. x0+35 (16B aligned)
            int p = sy * W + sx0;
            int pc = p < 0 ? 0 : (p > HW - 4 ? HW - 4 : p);
            bool qv = ((unsigned)sy < (unsigned)H) & ((unsigned)sx0 < (unsigned)W);

            float4 vfx = *(const float4*)(fxp + pc);
            float4 vfy = *(const float4*)(fyp + pc);
            float4 vim = *(const float4*)(imp_p + pc);
            float4 v0  = *(const float4*)(c0p + pc);
            float4 v1  = *(const float4*)(c1p + pc);
            float4 v2  = *(const float4*)(c2p + pc);
            float4 v3  = *(const float4*)(c3p + pc);

            float aflx[4] = {vfx.x, vfx.y, vfx.z, vfx.w};
            float afly[4] = {vfy.x, vfy.y, vfy.z, vfy.w};
            float aim [4] = {vim.x, vim.y, vim.z, vim.w};
            float a0  [4] = {v0.x,  v0.y,  v0.z,  v0.w};
            float a1  [4] = {v1.x,  v1.y,  v1.z,  v1.w};
            float a2  [4] = {v2.x,  v2.y,  v2.z,  v2.w};
            float a3  [4] = {v3.x,  v3.y,  v3.z,  v3.w};

            int base = r * LSTRIDE + c * 4;
            #pragma unroll
            for (int k = 0; k < 4; ++k) {
                float im = qv ? __expf(aim[k]) : 0.0f;   // im=0 kills invalid cells
                float txv = (float)(sx0 + k) + aflx[k];
                float tyv = (float)sy + afly[k];
                XY[base + k] = make_float2(txv, tyv);
                IM[base + k] = im;
                HPack hp;
                hp.a = __floats2half2_rn(a0[k] * im, a1[k] * im);
                hp.b = __floats2half2_rn(a2[k] * im, a3[k] * im);
                CH[base + k] = hp;
            }
        }
    }
    __syncthreads();

    // ---------- 2x2 quad register gather: thread owns rows {2qy,2qy+1},
    //            cols {2qx, 2qx+1} of the tile
    const int qx = tid & 15;
    const int qy = tid >> 4;
    const float ox0f = (float)(x0 + 2 * qx);
    const float oy0f = (float)(y0 + 2 * qy);

    float accw[4] = {0.f, 0.f, 0.f, 0.f};
    float acc0[4] = {0.f, 0.f, 0.f, 0.f};
    float acc1[4] = {0.f, 0.f, 0.f, 0.f};
    float acc2[4] = {0.f, 0.f, 0.f, 0.f};
    float acc3[4] = {0.f, 0.f, 0.f, 0.f};

    // staged row r = 2qy + dyi; staged col c = 2qx + 1 + dxi
    for (int dyi = 0; dyi < 8; ++dyi) {
        int rowoff = (2 * qy + dyi) * LSTRIDE + 2 * qx + 1;
        #pragma unroll
        for (int dxi = 0; dxi < 8; ++dxi) {
            float2 xy = XY[rowoff + dxi];
            float ddy = xy.y - oy0f;
            float wy0 = (dyi <= 6) ? fmaxf(0.0f, 1.0f - fabsf(ddy))        : 0.0f;
            float wy1 = (dyi >= 1) ? fmaxf(0.0f, 1.0f - fabsf(ddy - 1.0f)) : 0.0f;
            if (wy0 + wy1 > 0.0f) {
                float ddx = xy.x - ox0f;
                float wx0 = (dxi <= 6) ? fmaxf(0.0f, 1.0f - fabsf(ddx))        : 0.0f;
                float wx1 = (dxi >= 1) ? fmaxf(0.0f, 1.0f - fabsf(ddx - 1.0f)) : 0.0f;
                float t00 = wy0 * wx0, t01 = wy0 * wx1;
                float t10 = wy1 * wx0, t11 = wy1 * wx1;
                if ((t00 + t01) + (t10 + t11) > 0.0f) {   // any-hit
                    float im = IM[rowoff + dxi];
                    HPack hp = CH[rowoff + dxi];
                    float2 f01 = __half22float2(hp.a);
                    float2 f23 = __half22float2(hp.b);
                    accw[0] = fmaf(im, t00, accw[0]);
                    accw[1] = fmaf(im, t01, accw[1]);
                    accw[2] = fmaf(im, t10, accw[2]);
                    accw[3] = fmaf(im, t11, accw[3]);
                    acc0[0] = fmaf(f01.x, t00, acc0[0]);
                    acc0[1] = fmaf(f01.x, t01, acc0[1]);
                    acc0[2] = fmaf(f01.x, t10, acc0[2]);
                    acc0[3] = fmaf(f01.x, t11, acc0[3]);
                    acc1[0] = fmaf(f01.y, t00, acc1[0]);
                    acc1[1] = fmaf(f01.y, t01, acc1[1]);
                    acc1[2] = fmaf(f01.y, t10, acc1[2]);
                    acc1[3] = fmaf(f01.y, t11, acc1[3]);
                    acc2[0] = fmaf(f23.x, t00, acc2[0]);
                    acc2[1] = fmaf(f23.x, t01, acc2[1]);
                    acc2[2] = fmaf(f23.x, t10, acc2[2]);
                    acc2[3] = fmaf(f23.x, t11, acc2[3]);
                    acc3[0] = fmaf(f23.y, t00, acc3[0]);
                    acc3[1] = fmaf(f23.y, t01, acc3[1]);
                    acc3[2] = fmaf(f23.y, t10, acc3[2]);
                    acc3[3] = fmaf(f23.y, t11, acc3[3]);
                }
            }
        }
    }

    // ---------- per-tile bucket merge (mean ~6 entries; loads frame here)
    __syncthreads();
    const int tile = b * NTILE + blockIdx.y * NTILE_X + blockIdx.x;
    int cnt = bcnt[tile];
    if (cnt > BUCKET_CAP) cnt = BUCKET_CAP;
    if (cnt > 0) {                                     // uniform branch
        float* oacc = smem;                            // 5*1024 floats
        for (int i = tid; i < 5 * 1024; i += 256) oacc[i] = 0.0f;
        __syncthreads();
        const float* bb = bucket + (size_t)tile * BUCKET_CAP * 4;
        for (int e = tid; e < cnt; e += 256) {
            const float* ent = bb + (size_t)e * 4;
            int cell = __float_as_int(ent[0]);
            int p    = __float_as_int(ent[1]);
            float iw = ent[3] * ent[2];               // im * w
            atomicAdd(&oacc[0 * 1024 + cell], c0p[p] * iw);
            atomicAdd(&oacc[1 * 1024 + cell], c1p[p] * iw);
            atomicAdd(&oacc[2 * 1024 + cell], c2p[p] * iw);
            atomicAdd(&oacc[3 * 1024 + cell], c3p[p] * iw);
            atomicAdd(&oacc[4 * 1024 + cell], iw);
        }
        __syncthreads();
        #pragma unroll
        for (int k = 0; k < 2; ++k) {
            #pragma unroll
            for (int j = 0; j < 2; ++j) {
                int cell = (2 * qy + k) * TX + 2 * qx + j;
                int a = k * 2 + j;
                acc0[a] += oacc[0 * 1024 + cell];
                acc1[a] += oacc[1 * 1024 + cell];
                acc2[a] += oacc[2 * 1024 + cell];
                acc3[a] += oacc[3 * 1024 + cell];
                accw[a] += oacc[4 * 1024 + cell];
            }
        }
    }

    // ---------- fused normalize + float2 stores (lanes qx-consecutive)
    float inv[4];
    #pragma unroll
    for (int a = 0; a < 4; ++a) inv[a] = 1.0f / (accw[a] + EPS);

    #pragma unroll
    for (int k = 0; k < 2; ++k) {
        size_t obase = (size_t)b * CHW + (size_t)(y0 + 2 * qy + k) * W + (x0 + 2 * qx);
        int a0i = k * 2, a1i = k * 2 + 1;
        *(float2*)(out + obase + 0 * HW) = make_float2(acc0[a0i] * inv[a0i], acc0[a1i] * inv[a1i]);
        *(float2*)(out + obase + 1 * HW) = make_float2(acc1[a0i] * inv[a0i], acc1[a1i] * inv[a1i]);
        *(float2*)(out + obase + 2 * HW) = make_float2(acc2[a0i] * inv[a0i], acc2[a1i] * inv[a1i]);
        *(float2*)(out + obase + 3 * HW) = make_float2(acc3[a0i] * inv[a0i], acc3[a1i] * inv[a1i]);
    }
}

extern "C" void kernel_launch(void* const* d_in, const int* in_sizes, int n_in,
                              void* d_out, int out_size, void* d_ws, size_t ws_size,
                              hipStream_t stream) {
    const float* frame = (const float*)d_in[0];
    const float* flow  = (const float*)d_in[1];
    const float* imp   = (const float*)d_in[2];
    float* out = (float*)d_out;

    int*   bcnt   = (int*)d_ws;                         // 3840 * 4 B
    float* bucket = (float*)((char*)d_ws + 16384);      // 3840*64*16 B = 3.9 MB

    hipMemsetAsync(bcnt, 0, B * NTILE * sizeof(int), stream);

    outlier_pass<<<(NPIX / 4 + 255) / 256, 256, 0, stream>>>(flow, imp, bcnt, bucket);

    dim3 grid(W / TX, H / TY, B);   // 30 x 16 x 8
    splat_gather<<<grid, 256, 0, stream>>>(frame, flow, imp, out, bcnt, bucket);
}